// Round 18
// baseline (212.614 us; speedup 1.0000x reference)
//
#include <hip/hip_runtime.h>
#include <hip/hip_bf16.h>

typedef __hip_bfloat16 bf16;

#define NAG 256
#define HID 128
#define ACT 5
#define NH 4
#define DD 144      // concat dim
#define EE 576      // embed dim
#define HDIM 144    // per-head dim
#define CMAX 20     // fast-path neighbor cap

// ---------------------------------------------------------------------------
// Wave-split-K GEMM, XCD-swizzled, bf16 weights:
//   out[z][256 x N] = A[z][256 x 576] @ W[z][576 x N] (+ bscale[row]*b[z]).
// Block: 8 rows x 64 cols; 4 waves each take Kc=144; LDS reduce merges.
// G=36 W scalars (bf16->f32 at load) double-buffered in regs.
// ---------------------------------------------------------------------------
template<int KDIM, int AG, int NX, int GSLOTS>
__global__ __launch_bounds__(256) void k_gemmK(
    const float* __restrict__ A0, const float* __restrict__ A1, const float* __restrict__ A2,
    const bf16* __restrict__ W0, const bf16* __restrict__ W1, const bf16* __restrict__ W2,
    const float* __restrict__ bb0, const float* __restrict__ bb1, const float* __restrict__ bb2,
    const float* __restrict__ bscale,
    float* __restrict__ o0, float* __restrict__ o1, float* __restrict__ o2,
    int N)
{
    constexpr int Kc = KDIM / 4;               // per-wave K chunk (144)
    constexpr int G  = 36;
    constexpr int NG = Kc / G;                 // 4
    constexpr int LDA = KDIM + 4;
    __shared__ union { float As[8 * LDA]; float red[2048]; } sm;

    const int p = blockIdx.x;
    const int xcd = p & 7, qq = p >> 3;
    const int mb = qq & 31, gslot = qq >> 5;
    const int g = xcd + 8 * gslot;             // block-uniform
    if (g >= AG) return;                       // before any barrier: safe
    const int bx = g % NX, z = g / NX;
    const float* A   = (z == 0) ? A0  : (z == 1) ? A1  : A2;
    const bf16*  W   = (z == 0) ? W0  : (z == 1) ? W1  : W2;
    const float* bia = (z == 0) ? bb0 : (z == 1) ? bb1 : bb2;
    float*       out = (z == 0) ? o0  : (z == 1) ? o1  : o2;
    const int tid = threadIdx.x;

    for (int idx = tid; idx < 8 * (KDIM / 4); idx += 256) {
        int r = idx / (KDIM / 4), c = idx % (KDIM / 4);
        *((float4*)&sm.As[r * LDA + c * 4]) =
            *(const float4*)(A + (size_t)(mb * 8 + r) * KDIM + c * 4);
    }
    __syncthreads();

    const int wave = tid >> 6, lane = tid & 63;
    const int colg = bx * 64 + lane;
    const bool cv = colg < N;
    const int colc = cv ? colg : (N - 1);
    const bf16* Wp = W + (size_t)(wave * Kc) * N + colc;
    float acc[8] = {};
    float wv[G], wn[G];
    #pragma unroll
    for (int j = 0; j < G; ++j) wv[j] = __bfloat162float(Wp[(size_t)j * N]);
    for (int gi = 0; gi < NG; ++gi) {
        if (gi + 1 < NG) {
            const bf16* Wn = Wp + (size_t)(gi + 1) * G * N;
            #pragma unroll
            for (int j = 0; j < G; ++j) wn[j] = __bfloat162float(Wn[(size_t)j * N]);
        }
        const int kb = wave * Kc + gi * G;
        #pragma unroll
        for (int j4 = 0; j4 < G / 4; ++j4) {
            #pragma unroll
            for (int r = 0; r < 8; ++r) {
                float4 a4 = *(const float4*)&sm.As[r * LDA + kb + j4 * 4];
                acc[r] += a4.x * wv[j4 * 4 + 0] + a4.y * wv[j4 * 4 + 1]
                        + a4.z * wv[j4 * 4 + 2] + a4.w * wv[j4 * 4 + 3];
            }
        }
        #pragma unroll
        for (int j = 0; j < G; ++j) wv[j] = wn[j];
    }
    __syncthreads();                           // all waves done reading As
    #pragma unroll
    for (int r = 0; r < 8; ++r) sm.red[wave * 512 + r * 64 + lane] = acc[r];
    __syncthreads();
    #pragma unroll
    for (int q = 0; q < 2; ++q) {
        int idx = tid + q * 256;               // 512 outputs
        int r = idx >> 6, cl = idx & 63;
        int col = bx * 64 + cl;
        if (col < N) {
            float s = sm.red[idx] + sm.red[512 + idx]
                    + sm.red[1024 + idx] + sm.red[1536 + idx];
            int row = mb * 8 + r;
            float bs = bscale ? bscale[row] : 1.f;
            float bb = bia ? bia[col] : 0.f;
            out[(size_t)row * N + col] = s + bs * bb;
        }
    }
}

// ---------------------------------------------------------------------------
// gemm1 (fused obs-encoder, XCD-swizzled) + weight conversion in idle blocks.
// Blocks g<27 (864): Ct = concat(enc(hidden), action) in LDS; out = Ct@W_z+b.
// Blocks g>=27 (160): convert Wiq/Wik/Wiv/Wo/W_O fp32->bf16 (1,410,048 elems)
// concurrently with gemm1 compute; visible to gemm2 at kernel boundary.
// grid 1024.
// ---------------------------------------------------------------------------
__global__ __launch_bounds__(256) void k_gemm1(
    const float* __restrict__ hidden, const float* __restrict__ action,
    const float* __restrict__ W_enc, const float* __restrict__ b_enc,
    const float* __restrict__ Wq, const float* __restrict__ Wk, const float* __restrict__ Wv,
    const float* __restrict__ bq, const float* __restrict__ bk, const float* __restrict__ bv,
    const float* __restrict__ Wiq, const float* __restrict__ Wik, const float* __restrict__ Wiv,
    const float* __restrict__ Wo, const float* __restrict__ W_O,
    float* __restrict__ tq, float* __restrict__ tk, float* __restrict__ tv,
    bf16* __restrict__ Wbiq, bf16* __restrict__ Wbik, bf16* __restrict__ Wbiv,
    bf16* __restrict__ Wbo, bf16* __restrict__ WbO)
{
    const int p = blockIdx.x;
    const int xcd = p & 7, qq = p >> 3;
    const int mb = qq & 31, gslot = qq >> 5;
    const int g = xcd + 8 * gslot;             // block-uniform
    const int tid = threadIdx.x;
    if (g >= 27) {                             // conversion branch (160 blocks)
        const int wb = (g - 27) * 32 + mb;     // 0..159
        const int CH = 8832;                   // 160*8832 >= 1410048
        for (int i = wb * CH + tid; i < (wb + 1) * CH; i += 256) {
            if (i >= 1410048) break;
            if (i < 331776)        Wbiq[i]           = __float2bfloat16(Wiq[i]);
            else if (i < 663552)   Wbik[i - 331776]  = __float2bfloat16(Wik[i - 331776]);
            else if (i < 995328)   Wbiv[i - 663552]  = __float2bfloat16(Wiv[i - 663552]);
            else if (i < 1327104)  Wbo[i - 995328]   = __float2bfloat16(Wo[i - 995328]);
            else                   WbO[i - 1327104]  = __float2bfloat16(W_O[i - 1327104]);
        }
        return;
    }
    const int bx = g % 9, z = g / 9;
    const float* W  = (z == 0) ? Wq : (z == 1) ? Wk : Wv;
    const float* bi = (z == 0) ? bq : (z == 1) ? bk : bv;
    float*      out = (z == 0) ? tq : (z == 1) ? tk : tv;

    __shared__ float Ct[8][148];
    __shared__ union { struct { float Hs[8][132]; float We[2048]; } e;
                       float red[2048]; } u;
    {   // stage hidden rows, W_enc, action
        int r = tid >> 5, kq = tid & 31;
        *((float4*)&u.e.Hs[r][kq * 4]) =
            *(const float4*)(hidden + (mb * 8 + r) * HID + kq * 4);
        *((float4*)&Ct[r][16 + kq * 4]) =
            *(const float4*)(action + (mb * 8 + r) * HID + kq * 4);
        *((float4*)&u.e.We[tid * 4])        = *(const float4*)(W_enc + tid * 4);
        *((float4*)&u.e.We[1024 + tid * 4]) = *(const float4*)(W_enc + 1024 + tid * 4);
    }
    __syncthreads();
    if (tid < 128) {                           // enc: 8 rows x 16 outs (LDS only)
        int r = tid >> 4, o = tid & 15;
        float acc = 0.f;
        #pragma unroll 8
        for (int d = 0; d < HID; ++d) acc += u.e.Hs[r][d] * u.e.We[d * 16 + o];
        Ct[r][o] = acc + b_enc[o];
    }
    __syncthreads();

    constexpr int Kc = 36, G = 36;             // single load group
    const int wave = tid >> 6, lane = tid & 63;
    const int colg = bx * 64 + lane;
    const float* Wp = W + (size_t)(wave * Kc) * EE + colg;
    float acc[8] = {};
    float wv[G];
    #pragma unroll
    for (int j = 0; j < G; ++j) wv[j] = Wp[(size_t)j * EE];
    const int kb = wave * Kc;
    #pragma unroll
    for (int j4 = 0; j4 < G / 4; ++j4) {
        #pragma unroll
        for (int r = 0; r < 8; ++r) {
            float4 a4 = *(const float4*)&Ct[r][kb + j4 * 4];
            acc[r] += a4.x * wv[j4 * 4 + 0] + a4.y * wv[j4 * 4 + 1]
                    + a4.z * wv[j4 * 4 + 2] + a4.w * wv[j4 * 4 + 3];
        }
    }
    __syncthreads();                           // Hs/We dead; red overlays
    #pragma unroll
    for (int r = 0; r < 8; ++r) u.red[wave * 512 + r * 64 + lane] = acc[r];
    __syncthreads();
    #pragma unroll
    for (int q = 0; q < 2; ++q) {
        int idx = tid + q * 256;
        int r = idx >> 6, cl = idx & 63;
        int col = bx * 64 + cl;
        float s = u.red[idx] + u.red[512 + idx]
                + u.red[1024 + idx] + u.red[1536 + idx];
        out[(size_t)(mb * 8 + r) * EE + col] = s + bi[col];
    }
}

// ---------------------------------------------------------------------------
// Fused scores + attention reduction (proven rounds 8-17).
// ---------------------------------------------------------------------------
__global__ __launch_bounds__(256) void k_attn(
    const int* __restrict__ state, const float* __restrict__ q,
    const float* __restrict__ kmat, const float* __restrict__ v,
    float* __restrict__ ctxsum, float* __restrict__ cnt)
{
    __shared__ int lst[NAG];
    __shared__ int cnt_s;
    __shared__ float w4[NH][NAG];
    __shared__ float qh[CMAX][HDIM + 1];
    __shared__ float kh[CMAX][HDIM + 1];
    __shared__ float Sl[CMAX][CMAX + 1];
    const int i = blockIdx.x, tid = threadIdx.x;
    if (tid == 0) cnt_s = 0;
    __syncthreads();
    {
        int xi = state[2 * i], yi = state[2 * i + 1];
        int xj = state[2 * tid], yj = state[2 * tid + 1];
        int dx = xi - xj; if (dx < 0) dx = -dx;
        int dy = yi - yj; if (dy < 0) dy = -dy;
        if (tid > i && dx <= 4 && dy <= 2) {
            int p = atomicAdd(&cnt_s, 1);
            lst[p] = tid;
        }
    }
    __syncthreads();
    const int c = cnt_s;                 // block-uniform
    if (tid == 0) cnt[i] = (float)c;
    if (c == 0) {
        for (int e = tid; e < EE; e += 256) ctxsum[i * EE + e] = 0.f;
        return;
    }
    if (c <= CMAX) {
        for (int h = 0; h < NH; ++h) {
            for (int idx = tid; idx < c * HDIM; idx += 256) {
                int jj = idx / HDIM, d = idx % HDIM;
                qh[jj][d] = q[lst[jj] * EE + h * HDIM + d];
                kh[jj][d] = kmat[lst[jj] * EE + h * HDIM + d];
            }
            __syncthreads();
            for (int pp = tid; pp < c * c; pp += 256) {
                int jj = pp / c, kk = pp % c;
                float acc = 0.f;
                for (int d = 0; d < HDIM; ++d) acc += qh[jj][d] * kh[kk][d];
                Sl[jj][kk] = acc * (1.0f / 12.0f);
            }
            __syncthreads();
            if (tid < c) {
                float m = -1e30f;
                for (int kk = 0; kk < c; ++kk) m = fmaxf(m, Sl[tid][kk]);
                float zz = 0.f;
                for (int kk = 0; kk < c; ++kk) zz += __expf(Sl[tid][kk] - m);
                float inv = 1.f / fmaxf(zz, 1e-9f);
                for (int kk = 0; kk < c; ++kk)
                    Sl[tid][kk] = __expf(Sl[tid][kk] - m) * inv;
            }
            __syncthreads();
            if (tid < c) {
                float s = 0.f;
                for (int jj = 0; jj < c; ++jj) s += Sl[jj][tid];
                w4[h][tid] = s;
            }
            __syncthreads();
        }
    } else {
        for (int idx = tid; idx < NH * c; idx += 256) w4[idx / c][idx % c] = 0.f;
        __syncthreads();
        for (int pnh = tid; pnh < NH * c; pnh += 256) {
            int h = pnh / c, jj = pnh % c;
            const float* qrow = q + lst[jj] * EE + h * HDIM;
            float m = -1e30f;
            for (int kk = 0; kk < c; ++kk) {
                const float* krow = kmat + lst[kk] * EE + h * HDIM;
                float a = 0.f;
                for (int d = 0; d < HDIM; ++d) a += qrow[d] * krow[d];
                m = fmaxf(m, a * (1.0f / 12.0f));
            }
            float zz = 0.f;
            for (int kk = 0; kk < c; ++kk) {
                const float* krow = kmat + lst[kk] * EE + h * HDIM;
                float a = 0.f;
                for (int d = 0; d < HDIM; ++d) a += qrow[d] * krow[d];
                zz += __expf(a * (1.0f / 12.0f) - m);
            }
            float inv = 1.f / fmaxf(zz, 1e-9f);
            for (int kk = 0; kk < c; ++kk) {
                const float* krow = kmat + lst[kk] * EE + h * HDIM;
                float a = 0.f;
                for (int d = 0; d < HDIM; ++d) a += qrow[d] * krow[d];
                atomicAdd(&w4[h][kk], __expf(a * (1.0f / 12.0f) - m) * inv);
            }
        }
        __syncthreads();
    }
    for (int e = tid; e < EE; e += 256) {
        int h = e / HDIM;
        float a0 = 0.f, a1 = 0.f;
        int t = 0;
        for (; t + 1 < c; t += 2) {
            a0 += w4[h][t] * v[lst[t] * EE + e];
            a1 += w4[h][t + 1] * v[lst[t + 1] * EE + e];
        }
        if (t < c) a0 += w4[h][t] * v[lst[t] * EE + e];
        ctxsum[i * EE + e] = a0 + a1;
    }
}

// ---------------------------------------------------------------------------
// Fused gemm4 + dueling head. 64 blocks x 4 agents:
//   hb[4 x 144] = tout[4 rows x 576] @ W_O (bf16, G=32 reg double-buffer),
//   Q[agent]    = dueling head (one wave per agent).
// ---------------------------------------------------------------------------
__global__ __launch_bounds__(256) void k_tail(
    const float* __restrict__ tout, const bf16* __restrict__ WbO,
    const float* __restrict__ W_val, const float* __restrict__ b_val,
    const float* __restrict__ W_adv, const float* __restrict__ b_adv,
    float* __restrict__ out)
{
    __shared__ float As[4][EE];
    __shared__ float hb[4][DD];
    const int b = blockIdx.x, tid = threadIdx.x;
    const int a0 = b * 4;
    for (int idx = tid; idx < 4 * (EE / 4); idx += 256) {
        int r = idx / (EE / 4), c4 = idx % (EE / 4);
        *((float4*)&As[r][c4 * 4]) =
            *(const float4*)(tout + (size_t)(a0 + r) * EE + c4 * 4);
    }
    __syncthreads();
    if (tid < DD) {
        const int col = tid;
        const bf16* Wp = WbO + col;
        float ac0 = 0.f, ac1 = 0.f, ac2 = 0.f, ac3 = 0.f;
        float wv[32], wn[32];
        #pragma unroll
        for (int j = 0; j < 32; ++j) wv[j] = __bfloat162float(Wp[(size_t)j * DD]);
        for (int gI = 0; gI < 18; ++gI) {
            if (gI + 1 < 18) {
                const bf16* Wn = Wp + (size_t)(gI + 1) * 32 * DD;
                #pragma unroll
                for (int j = 0; j < 32; ++j) wn[j] = __bfloat162float(Wn[(size_t)j * DD]);
            }
            const int kb = gI * 32;
            #pragma unroll
            for (int j = 0; j < 32; ++j) {
                float w = wv[j];
                ac0 += As[0][kb + j] * w; ac1 += As[1][kb + j] * w;
                ac2 += As[2][kb + j] * w; ac3 += As[3][kb + j] * w;
            }
            #pragma unroll
            for (int j = 0; j < 32; ++j) wv[j] = wn[j];
        }
        hb[0][col] = ac0; hb[1][col] = ac1; hb[2][col] = ac2; hb[3][col] = ac3;
    }
    __syncthreads();
    // head: wave w -> agent a0 + w
    const int wave = tid >> 6, lane = tid & 63;
    float h0 = hb[wave][lane], h1 = hb[wave][lane + 64];
    float h2 = (lane < 16) ? hb[wave][lane + 128] : 0.f;
    float red[6];
    for (int o = 0; o < 6; ++o) {
        float p;
        if (o < 5) {
            p = h0 * W_adv[lane * ACT + o] + h1 * W_adv[(lane + 64) * ACT + o];
            if (lane < 16) p += h2 * W_adv[(lane + 128) * ACT + o];
        } else {
            p = h0 * W_val[lane] + h1 * W_val[lane + 64];
            if (lane < 16) p += h2 * W_val[lane + 128];
        }
        for (int off = 32; off; off >>= 1) p += __shfl_xor(p, off);
        red[o] = p;
    }
    if (lane == 0) {
        float a[ACT], mean = 0.f;
        for (int o = 0; o < ACT; ++o) { a[o] = red[o] + b_adv[o]; mean += a[o]; }
        mean *= (1.0f / ACT);
        float V = red[5] + b_val[0];
        for (int o = 0; o < ACT; ++o) out[(a0 + wave) * ACT + o] = V + a[o] - mean;
    }
}

// ---------------------------------------------------------------------------
extern "C" void kernel_launch(void* const* d_in, const int* in_sizes, int n_in,
                              void* d_out, int out_size, void* d_ws, size_t ws_size,
                              hipStream_t stream)
{
    const float* hidden = (const float*)d_in[0];
    const float* action = (const float*)d_in[1];
    const int*   state  = (const int*)d_in[2];

    float* ws = (float*)d_ws;
    float* tq   = ws;                        // 256*576 each
    float* tk   = tq   + NAG * EE;
    float* tv   = tk   + NAG * EE;
    float* q    = tv   + NAG * EE;
    float* kb   = q    + NAG * EE;
    float* v    = kb   + NAG * EE;
    float* ctx  = v    + NAG * EE;
    float* cnt  = ctx  + NAG * EE;           // 256
    bf16*  bw   = (bf16*)(cnt + NAG);        // bf16 weight region (2.8 MB)
    bf16*  Wbiq = bw;                        // 331776 each (Wiq/Wik/Wiv/Wo)
    bf16*  Wbik = Wbiq + 331776;
    bf16*  Wbiv = Wbik + 331776;
    bf16*  Wbo  = Wbiv + 331776;
    bf16*  WbO  = Wbo  + 331776;             // 82944
    float* tout = tq;                        // alias: tq dead after gemm2
    // ws use ~7 MB; ws_size measured 256 MB (fill WRITE_SIZE) -> ample

    // gemm1 (fused enc) + fp32->bf16 weight conversion in idle blocks
    k_gemm1<<<1024, 256, 0, stream>>>(hidden, action,
        (const float*)d_in[3], (const float*)d_in[4],
        (const float*)d_in[5], (const float*)d_in[7], (const float*)d_in[9],
        (const float*)d_in[6], (const float*)d_in[8], (const float*)d_in[10],
        (const float*)d_in[11], (const float*)d_in[13], (const float*)d_in[15],
        (const float*)d_in[17], (const float*)d_in[19],
        tq, tk, tv, Wbiq, Wbik, Wbiv, Wbo, WbO);

    // gemm2: {q,k,v} = t @ Wi*(bf16) + bi  (27 strips, swizzled, 864 active)
    k_gemmK<576, 27, 9, 4><<<1024, 256, 0, stream>>>(tq, tk, tv,
        Wbiq, Wbik, Wbiv,
        (const float*)d_in[12], (const float*)d_in[14], (const float*)d_in[16],
        nullptr, q, kb, v, EE);

    // fused scores+attention
    k_attn<<<NAG, 256, 0, stream>>>(state, q, kb, v, ctx, cnt);

    // gemm3: tout = ctx @ Wo(bf16) + cnt*bo  (9 strips, swizzled, 288 active)
    k_gemmK<576, 9, 9, 2><<<512, 256, 0, stream>>>(ctx, ctx, ctx,
        Wbo, Wbo, Wbo,
        (const float*)d_in[18], (const float*)d_in[18], (const float*)d_in[18],
        cnt, tout, tout, tout, EE);

    // fused gemm4 + head
    k_tail<<<64, 256, 0, stream>>>(tout, WbO,
        (const float*)d_in[20], (const float*)d_in[21],
        (const float*)d_in[22], (const float*)d_in[23], (float*)d_out);
}

// Round 19
// 191.857 us; speedup vs baseline: 1.1082x; 1.1082x over previous
//
#include <hip/hip_runtime.h>
#include <hip/hip_bf16.h>

#define NAG 256
#define HID 128
#define ACT 5
#define NH 4
#define DD 144      // concat dim
#define EE 576      // embed dim
#define HDIM 144    // per-head dim
#define CMAX 20     // fast-path neighbor cap

// ---------------------------------------------------------------------------
// Wave-split-K product tile: out[rowbase..+8, colbase..+64] =
//   A[rowbase..+8, 0..576) @ W[576 x N], A row-major stride 576.
// 4 waves split K (Kc=144); G=36 register double-buffer; LDS reduce.
// sm must hold >= 4640 floats (As 8x580, then red 2048 aliased).
// ---------------------------------------------------------------------------
__device__ __forceinline__ void prod_tile(
    const float* __restrict__ A, const float* __restrict__ W,
    float* __restrict__ out, int rowbase, int colbase, int N,
    int tid, float* sm)
{
    const int LDA = 580;
    float* As = sm;
    for (int idx = tid; idx < 8 * 144; idx += 256) {
        int r = idx / 144, c = idx % 144;
        *((float4*)&As[r * LDA + c * 4]) =
            *(const float4*)(A + (size_t)(rowbase + r) * 576 + c * 4);
    }
    __syncthreads();
    const int wave = tid >> 6, lane = tid & 63;
    const int colg = colbase + lane;
    const int colc = (colg < N) ? colg : (N - 1);
    const float* Wp = W + (size_t)(wave * 144) * N + colc;
    float acc[8] = {};
    float wv[36], wn[36];
    #pragma unroll
    for (int j = 0; j < 36; ++j) wv[j] = Wp[(size_t)j * N];
    for (int gi = 0; gi < 4; ++gi) {
        if (gi + 1 < 4) {
            const float* Wn = Wp + (size_t)(gi + 1) * 36 * N;
            #pragma unroll
            for (int j = 0; j < 36; ++j) wn[j] = Wn[(size_t)j * N];
        }
        const int kb = wave * 144 + gi * 36;
        #pragma unroll
        for (int j4 = 0; j4 < 9; ++j4) {
            #pragma unroll
            for (int r = 0; r < 8; ++r) {
                float4 a4 = *(const float4*)&As[r * LDA + kb + j4 * 4];
                acc[r] += a4.x * wv[j4 * 4 + 0] + a4.y * wv[j4 * 4 + 1]
                        + a4.z * wv[j4 * 4 + 2] + a4.w * wv[j4 * 4 + 3];
            }
        }
        #pragma unroll
        for (int j = 0; j < 36; ++j) wv[j] = wn[j];
    }
    __syncthreads();
    float* red = sm;
    #pragma unroll
    for (int r = 0; r < 8; ++r) red[wave * 512 + r * 64 + lane] = acc[r];
    __syncthreads();
    #pragma unroll
    for (int q = 0; q < 2; ++q) {
        int idx = tid + q * 256;
        int r = idx >> 6, cl = idx & 63;
        int col = colbase + cl;
        if (col < N) {
            float s = red[idx] + red[512 + idx] + red[1024 + idx] + red[1536 + idx];
            out[(size_t)(rowbase + r) * N + col] = s;
        }
    }
}

// ---------------------------------------------------------------------------
// k_pre (one dispatch, 1214 blocks): everything that depends only on weights
// plus the obs-encoder.
//  [0,576)     qkv products: Wzc = Wz @ Wiz   (z=q,k,v; 486 active, swizzled)
//  [576,1152)  Wc = Wo @ W_O                  (216 active)
//  [1152,1184) C  = concat(enc(hidden), action)  (32 blocks)
//  [1184,1214) bzc = bz@Wiz + biz (27) ; bvec = bo@W_O (3)
// ---------------------------------------------------------------------------
__global__ __launch_bounds__(256) void k_pre(
    const float* __restrict__ hidden, const float* __restrict__ action,
    const float* __restrict__ W_enc, const float* __restrict__ b_enc,
    const float* __restrict__ Wq, const float* __restrict__ Wk, const float* __restrict__ Wv,
    const float* __restrict__ bq, const float* __restrict__ bk, const float* __restrict__ bv,
    const float* __restrict__ Wiq, const float* __restrict__ Wik, const float* __restrict__ Wiv,
    const float* __restrict__ biq, const float* __restrict__ bik, const float* __restrict__ biv,
    const float* __restrict__ Wo, const float* __restrict__ bo, const float* __restrict__ W_O,
    float* __restrict__ C,
    float* __restrict__ Wqc, float* __restrict__ Wkc, float* __restrict__ Wvc,
    float* __restrict__ Wc,
    float* __restrict__ bqc, float* __restrict__ bkc, float* __restrict__ bvc,
    float* __restrict__ bvec)
{
    __shared__ float sm[4640];
    const int p = blockIdx.x, tid = threadIdx.x;
    if (p < 576) {                             // qkv weight products
        const int xcd = p & 7, r = p >> 3;
        const int gslot = r / 18, mb = r % 18;
        const int g = xcd + 8 * gslot;         // block-uniform
        if (g >= 27) return;
        const int bx = g % 9, z = g / 9;
        const float* A = (z == 0) ? Wq  : (z == 1) ? Wk  : Wv;
        const float* W = (z == 0) ? Wiq : (z == 1) ? Wik : Wiv;
        float*     out = (z == 0) ? Wqc : (z == 1) ? Wkc : Wvc;
        prod_tile(A, W, out, mb * 8, bx * 64, EE, tid, sm);
    } else if (p < 1152) {                     // Wc = Wo @ W_O
        const int pp = p - 576;
        const int xcd = pp & 7, mb = pp >> 3;  // mb 0..71
        if (xcd >= 3) return;
        prod_tile(Wo, W_O, Wc, mb * 8, xcd * 64, DD, tid, sm);
    } else if (p < 1184) {                     // enc C
        const int mb = p - 1152;
        float* Hs = sm;                        // 8 x 132
        float* We = sm + 1056;                 // 2048
        {
            int r = tid >> 5, kq = tid & 31;
            *((float4*)&Hs[r * 132 + kq * 4]) =
                *(const float4*)(hidden + (mb * 8 + r) * HID + kq * 4);
            // action copy: straight through regs
            float4 a4 = *(const float4*)(action + (mb * 8 + r) * HID + kq * 4);
            *((float4*)(C + (size_t)(mb * 8 + r) * DD + 16 + kq * 4)) = a4;
            *((float4*)&We[tid * 4])        = *(const float4*)(W_enc + tid * 4);
            *((float4*)&We[1024 + tid * 4]) = *(const float4*)(W_enc + 1024 + tid * 4);
        }
        __syncthreads();
        if (tid < 128) {
            int r = tid >> 4, o = tid & 15;
            float acc = 0.f;
            #pragma unroll 8
            for (int d = 0; d < HID; ++d) acc += Hs[r * 132 + d] * We[d * 16 + o];
            C[(size_t)(mb * 8 + r) * DD + o] = acc + b_enc[o];
        }
    } else {                                   // bias vectors
        const int t = p - 1184;
        const float *bsel, *W, *badd;
        float* out;
        int N, bx;
        if (t < 27) {
            int z = t / 9; bx = t % 9; N = EE;
            bsel = (z == 0) ? bq  : (z == 1) ? bk  : bv;
            W    = (z == 0) ? Wiq : (z == 1) ? Wik : Wiv;
            badd = (z == 0) ? biq : (z == 1) ? bik : biv;
            out  = (z == 0) ? bqc : (z == 1) ? bkc : bvc;
        } else {
            bx = t - 27; N = DD;
            bsel = bo; W = W_O; badd = nullptr; out = bvec;
        }
        float* bs = sm;                        // 576
        float* red = sm + 576;                 // 256
        for (int i = tid; i < 144; i += 256)
            *((float4*)&bs[i * 4]) = *(const float4*)(bsel + i * 4);
        __syncthreads();
        const int wave = tid >> 6, lane = tid & 63;
        const int colg = bx * 64 + lane;
        const int colc = (colg < N) ? colg : (N - 1);
        float acc = 0.f;
        for (int k = wave * 144; k < wave * 144 + 144; ++k)
            acc += bs[k] * W[(size_t)k * N + colc];
        red[wave * 64 + lane] = acc;
        __syncthreads();
        if (tid < 64 && bx * 64 + tid < N) {
            float s = red[tid] + red[64 + tid] + red[128 + tid] + red[192 + tid];
            out[bx * 64 + tid] = s + (badd ? badd[bx * 64 + tid] : 0.f);
        }
    }
}

// ---------------------------------------------------------------------------
// k_qkv: {q,k,v} = C @ Wzc + bzc  (M=256, K=144, N=576), XCD-swizzled.
// 8-row tiles; wave Kc=36, single 36-load group; LDS reduce. grid 1024.
// ---------------------------------------------------------------------------
__global__ __launch_bounds__(256) void k_qkv(
    const float* __restrict__ C,
    const float* __restrict__ Wqc, const float* __restrict__ Wkc, const float* __restrict__ Wvc,
    const float* __restrict__ bqc, const float* __restrict__ bkc, const float* __restrict__ bvc,
    float* __restrict__ q, float* __restrict__ kb, float* __restrict__ v)
{
    const int p = blockIdx.x;
    const int xcd = p & 7, qq = p >> 3;
    const int mb = qq & 31, gslot = qq >> 5;
    const int g = xcd + 8 * gslot;             // block-uniform
    if (g >= 27) return;
    const int bx = g % 9, z = g / 9;
    const float* W  = (z == 0) ? Wqc : (z == 1) ? Wkc : Wvc;
    const float* bi = (z == 0) ? bqc : (z == 1) ? bkc : bvc;
    float*      out = (z == 0) ? q   : (z == 1) ? kb  : v;
    const int tid = threadIdx.x;

    __shared__ union { float As[8 * 148]; float red[2048]; } u;
    for (int idx = tid; idx < 8 * 36; idx += 256) {
        int r = idx / 36, c = idx % 36;
        *((float4*)&u.As[r * 148 + c * 4]) =
            *(const float4*)(C + (size_t)(mb * 8 + r) * DD + c * 4);
    }
    __syncthreads();
    const int wave = tid >> 6, lane = tid & 63;
    const int colg = bx * 64 + lane;
    const float* Wp = W + (size_t)(wave * 36) * EE + colg;
    float acc[8] = {};
    float wv[36];
    #pragma unroll
    for (int j = 0; j < 36; ++j) wv[j] = Wp[(size_t)j * EE];
    const int kbase = wave * 36;
    #pragma unroll
    for (int j4 = 0; j4 < 9; ++j4) {
        #pragma unroll
        for (int r = 0; r < 8; ++r) {
            float4 a4 = *(const float4*)&u.As[r * 148 + kbase + j4 * 4];
            acc[r] += a4.x * wv[j4 * 4 + 0] + a4.y * wv[j4 * 4 + 1]
                    + a4.z * wv[j4 * 4 + 2] + a4.w * wv[j4 * 4 + 3];
        }
    }
    __syncthreads();
    #pragma unroll
    for (int r = 0; r < 8; ++r) u.red[wave * 512 + r * 64 + lane] = acc[r];
    __syncthreads();
    #pragma unroll
    for (int qi = 0; qi < 2; ++qi) {
        int idx = tid + qi * 256;
        int r = idx >> 6, cl = idx & 63;
        int col = bx * 64 + cl;
        float s = u.red[idx] + u.red[512 + idx]
                + u.red[1024 + idx] + u.red[1536 + idx];
        out[(size_t)(mb * 8 + r) * EE + col] = s + bi[col];
    }
}

// ---------------------------------------------------------------------------
// Fused scores + attention reduction (proven rounds 8-18).
// ---------------------------------------------------------------------------
__global__ __launch_bounds__(256) void k_attn(
    const int* __restrict__ state, const float* __restrict__ q,
    const float* __restrict__ kmat, const float* __restrict__ v,
    float* __restrict__ ctxsum, float* __restrict__ cnt)
{
    __shared__ int lst[NAG];
    __shared__ int cnt_s;
    __shared__ float w4[NH][NAG];
    __shared__ float qh[CMAX][HDIM + 1];
    __shared__ float kh[CMAX][HDIM + 1];
    __shared__ float Sl[CMAX][CMAX + 1];
    const int i = blockIdx.x, tid = threadIdx.x;
    if (tid == 0) cnt_s = 0;
    __syncthreads();
    {
        int xi = state[2 * i], yi = state[2 * i + 1];
        int xj = state[2 * tid], yj = state[2 * tid + 1];
        int dx = xi - xj; if (dx < 0) dx = -dx;
        int dy = yi - yj; if (dy < 0) dy = -dy;
        if (tid > i && dx <= 4 && dy <= 2) {
            int p = atomicAdd(&cnt_s, 1);
            lst[p] = tid;
        }
    }
    __syncthreads();
    const int c = cnt_s;                 // block-uniform
    if (tid == 0) cnt[i] = (float)c;
    if (c == 0) {
        for (int e = tid; e < EE; e += 256) ctxsum[i * EE + e] = 0.f;
        return;
    }
    if (c <= CMAX) {
        for (int h = 0; h < NH; ++h) {
            for (int idx = tid; idx < c * HDIM; idx += 256) {
                int jj = idx / HDIM, d = idx % HDIM;
                qh[jj][d] = q[lst[jj] * EE + h * HDIM + d];
                kh[jj][d] = kmat[lst[jj] * EE + h * HDIM + d];
            }
            __syncthreads();
            for (int pp = tid; pp < c * c; pp += 256) {
                int jj = pp / c, kk = pp % c;
                float acc = 0.f;
                for (int d = 0; d < HDIM; ++d) acc += qh[jj][d] * kh[kk][d];
                Sl[jj][kk] = acc * (1.0f / 12.0f);
            }
            __syncthreads();
            if (tid < c) {
                float m = -1e30f;
                for (int kk = 0; kk < c; ++kk) m = fmaxf(m, Sl[tid][kk]);
                float zz = 0.f;
                for (int kk = 0; kk < c; ++kk) zz += __expf(Sl[tid][kk] - m);
                float inv = 1.f / fmaxf(zz, 1e-9f);
                for (int kk = 0; kk < c; ++kk)
                    Sl[tid][kk] = __expf(Sl[tid][kk] - m) * inv;
            }
            __syncthreads();
            if (tid < c) {
                float s = 0.f;
                for (int jj = 0; jj < c; ++jj) s += Sl[jj][tid];
                w4[h][tid] = s;
            }
            __syncthreads();
        }
    } else {
        for (int idx = tid; idx < NH * c; idx += 256) w4[idx / c][idx % c] = 0.f;
        __syncthreads();
        for (int pnh = tid; pnh < NH * c; pnh += 256) {
            int h = pnh / c, jj = pnh % c;
            const float* qrow = q + lst[jj] * EE + h * HDIM;
            float m = -1e30f;
            for (int kk = 0; kk < c; ++kk) {
                const float* krow = kmat + lst[kk] * EE + h * HDIM;
                float a = 0.f;
                for (int d = 0; d < HDIM; ++d) a += qrow[d] * krow[d];
                m = fmaxf(m, a * (1.0f / 12.0f));
            }
            float zz = 0.f;
            for (int kk = 0; kk < c; ++kk) {
                const float* krow = kmat + lst[kk] * EE + h * HDIM;
                float a = 0.f;
                for (int d = 0; d < HDIM; ++d) a += qrow[d] * krow[d];
                zz += __expf(a * (1.0f / 12.0f) - m);
            }
            float inv = 1.f / fmaxf(zz, 1e-9f);
            for (int kk = 0; kk < c; ++kk) {
                const float* krow = kmat + lst[kk] * EE + h * HDIM;
                float a = 0.f;
                for (int d = 0; d < HDIM; ++d) a += qrow[d] * krow[d];
                atomicAdd(&w4[h][kk], __expf(a * (1.0f / 12.0f) - m) * inv);
            }
        }
        __syncthreads();
    }
    for (int e = tid; e < EE; e += 256) {
        int h = e / HDIM;
        float a0 = 0.f, a1 = 0.f;
        int t = 0;
        for (; t + 1 < c; t += 2) {
            a0 += w4[h][t] * v[lst[t] * EE + e];
            a1 += w4[h][t + 1] * v[lst[t + 1] * EE + e];
        }
        if (t < c) a0 += w4[h][t] * v[lst[t] * EE + e];
        ctxsum[i * EE + e] = a0 + a1;
    }
}

// ---------------------------------------------------------------------------
// k_tail: h[4 x 144] = ctx[4 rows x 576] @ Wc + cnt*bvec; then dueling head.
// 64 blocks x 4 agents; 144 threads compute cols (G=32 reg double-buffer);
// head: one wave per agent.
// ---------------------------------------------------------------------------
__global__ __launch_bounds__(256) void k_tail(
    const float* __restrict__ ctx, const float* __restrict__ Wc,
    const float* __restrict__ cnt, const float* __restrict__ bvec,
    const float* __restrict__ W_val, const float* __restrict__ b_val,
    const float* __restrict__ W_adv, const float* __restrict__ b_adv,
    float* __restrict__ out)
{
    __shared__ float As[4][EE];
    __shared__ float hb[4][DD];
    const int b = blockIdx.x, tid = threadIdx.x;
    const int a0 = b * 4;
    for (int idx = tid; idx < 4 * (EE / 4); idx += 256) {
        int r = idx / (EE / 4), c4 = idx % (EE / 4);
        *((float4*)&As[r][c4 * 4]) =
            *(const float4*)(ctx + (size_t)(a0 + r) * EE + c4 * 4);
    }
    __syncthreads();
    if (tid < DD) {
        const int col = tid;
        const float* Wp = Wc + col;
        float ac0 = 0.f, ac1 = 0.f, ac2 = 0.f, ac3 = 0.f;
        float wv[32], wn[32];
        #pragma unroll
        for (int j = 0; j < 32; ++j) wv[j] = Wp[(size_t)j * DD];
        for (int gI = 0; gI < 18; ++gI) {
            if (gI + 1 < 18) {
                const float* Wn = Wp + (size_t)(gI + 1) * 32 * DD;
                #pragma unroll
                for (int j = 0; j < 32; ++j) wn[j] = Wn[(size_t)j * DD];
            }
            const int kbase = gI * 32;
            #pragma unroll
            for (int j = 0; j < 32; ++j) {
                float w = wv[j];
                ac0 += As[0][kbase + j] * w; ac1 += As[1][kbase + j] * w;
                ac2 += As[2][kbase + j] * w; ac3 += As[3][kbase + j] * w;
            }
            #pragma unroll
            for (int j = 0; j < 32; ++j) wv[j] = wn[j];
        }
        float bvc = bvec[col];
        hb[0][col] = ac0 + cnt[a0 + 0] * bvc;
        hb[1][col] = ac1 + cnt[a0 + 1] * bvc;
        hb[2][col] = ac2 + cnt[a0 + 2] * bvc;
        hb[3][col] = ac3 + cnt[a0 + 3] * bvc;
    }
    __syncthreads();
    const int wave = tid >> 6, lane = tid & 63;
    float h0 = hb[wave][lane], h1 = hb[wave][lane + 64];
    float h2 = (lane < 16) ? hb[wave][lane + 128] : 0.f;
    float red[6];
    for (int o = 0; o < 6; ++o) {
        float p;
        if (o < 5) {
            p = h0 * W_adv[lane * ACT + o] + h1 * W_adv[(lane + 64) * ACT + o];
            if (lane < 16) p += h2 * W_adv[(lane + 128) * ACT + o];
        } else {
            p = h0 * W_val[lane] + h1 * W_val[lane + 64];
            if (lane < 16) p += h2 * W_val[lane + 128];
        }
        for (int off = 32; off; off >>= 1) p += __shfl_xor(p, off);
        red[o] = p;
    }
    if (lane == 0) {
        float a[ACT], mean = 0.f;
        for (int o = 0; o < ACT; ++o) { a[o] = red[o] + b_adv[o]; mean += a[o]; }
        mean *= (1.0f / ACT);
        float V = red[5] + b_val[0];
        for (int o = 0; o < ACT; ++o) out[(a0 + wave) * ACT + o] = V + a[o] - mean;
    }
}

// ---------------------------------------------------------------------------
extern "C" void kernel_launch(void* const* d_in, const int* in_sizes, int n_in,
                              void* d_out, int out_size, void* d_ws, size_t ws_size,
                              hipStream_t stream)
{
    const float* hidden = (const float*)d_in[0];
    const float* action = (const float*)d_in[1];
    const int*   state  = (const int*)d_in[2];

    float* ws = (float*)d_ws;
    float* C    = ws;                        // 256*144 = 36864
    float* Wqc  = C    + NAG * DD;           // 144*576 = 82944 each
    float* Wkc  = Wqc  + DD * EE;
    float* Wvc  = Wkc  + DD * EE;
    float* Wc   = Wvc  + DD * EE;            // 576*144 = 82944
    float* bqc  = Wc   + EE * DD;            // 576 each
    float* bkc  = bqc  + EE;
    float* bvc  = bkc  + EE;
    float* bvec = bvc  + EE;                 // 144
    float* q    = bvec + DD;                 // 256*576 each
    float* kb   = q    + NAG * EE;
    float* v    = kb   + NAG * EE;
    float* ctx  = v    + NAG * EE;
    float* cnt  = ctx  + NAG * EE;           // 256
    // total ws ~3.9 MB

    // k_pre: weight products + biases + enc C  (1214 blocks, one dispatch)
    k_pre<<<1214, 256, 0, stream>>>(hidden, action,
        (const float*)d_in[3], (const float*)d_in[4],
        (const float*)d_in[5], (const float*)d_in[7], (const float*)d_in[9],
        (const float*)d_in[6], (const float*)d_in[8], (const float*)d_in[10],
        (const float*)d_in[11], (const float*)d_in[13], (const float*)d_in[15],
        (const float*)d_in[12], (const float*)d_in[14], (const float*)d_in[16],
        (const float*)d_in[17], (const float*)d_in[18], (const float*)d_in[19],
        C, Wqc, Wkc, Wvc, Wc, bqc, bkc, bvc, bvec);

    // k_qkv: q/k/v = C @ Wzc + bzc  (K=144, swizzled, 864 active)
    k_qkv<<<1024, 256, 0, stream>>>(C, Wqc, Wkc, Wvc, bqc, bkc, bvc, q, kb, v);

    // fused scores+attention
    k_attn<<<NAG, 256, 0, stream>>>(state, q, kb, v, ctx, cnt);

    // k_tail: h = ctx @ Wc + cnt*bvec; dueling head
    k_tail<<<64, 256, 0, stream>>>(ctx, Wc, cnt, bvec,
        (const float*)d_in[20], (const float*)d_in[21],
        (const float*)d_in[22], (const float*)d_in[23], (float*)d_out);
}